// Round 3
// baseline (267.233 us; speedup 1.0000x reference)
//
#include <hip/hip_runtime.h>
#include <hip/hip_bf16.h>

// Problem constants
#define HB 1024   // NUM_BASIC (GEMM K)
#define HM 8192   // NUM_MIXED (GEMM M, = j rows)
#define NR 735    // 105*7 actual GEMM N
#define NPAD 768  // padded N (4 waves x 192)
#define NOUT 57   // output is (HM, 57, 57)
#define BM 32     // j-rows per block -> 256 blocks = 1/CU
#define YS 736    // ly row stride in floats

typedef __attribute__((ext_vector_type(8))) _Float16 half8;
typedef __attribute__((ext_vector_type(4))) _Float16 half4v;
typedef __attribute__((ext_vector_type(4))) float floatx4;

// ---------------------------------------------------------------------------
// Kernel 1: build x2[r][h] = relu(te[h,t]*mat[h,n,m]) as fp16, padded to 768
// rows (zeros), K(h)-contiguous. r = (t*7+m)*7 + n
// ---------------------------------------------------------------------------
__global__ __launch_bounds__(256) void prep_x2_kernel(
    const float* __restrict__ mat, const float* __restrict__ tex,
    _Float16* __restrict__ Xh) {
  const int r = blockIdx.x;
  const int n = r % 7;
  const int tm = r / 7;
  const int m = tm % 7;
  const int t = tm / 7;
#pragma unroll
  for (int i = 0; i < 4; ++i) {
    const int h = i * 256 + threadIdx.x;
    float v = 0.f;
    if (r < NR) {
      const float mv = mat[h * 49 + n * 7 + m];
      const float te = 1.f / (1.f + expf(-tex[h * 15 + t])) + 1.f;
      v = te * mv;
      v = v > 0.f ? v : 0.f;  // relu
    }
    Xh[r * HB + h] = (_Float16)v;
  }
}

// ---------------------------------------------------------------------------
// Kernel 2: fused GEMM (M=32 x N=768 x K=1024) + bias/relu + block-build +
// degree-normalize + output write. One block per 32 j-rows (grid=256=1/CU).
// LDS: dbuf staging [As0 2K][As1 2K][Bs0 48K][Bs1 48K] = 100 KB, then reused
// as [ly 32x736 f32 = 92K][dd 32x57 f32 = 7.1K].
// W fp32->fp16 converted inline (each element read exactly once).
// ---------------------------------------------------------------------------
__global__ __launch_bounds__(256, 1) void fused_kernel(
    const float* __restrict__ W,    // [8192][1024] fp32
    const _Float16* __restrict__ Xh,  // [768][1024] fp16
    const float* __restrict__ bias, // [8192]
    float* __restrict__ out) {      // [8192][57*57]
  extern __shared__ char smem[];
  _Float16* const As0 = (_Float16*)smem;             // 2048 B
  _Float16* const As1 = (_Float16*)(smem + 2048);    // 2048 B
  _Float16* const Bs0 = (_Float16*)(smem + 4096);    // 49152 B
  _Float16* const Bs1 = (_Float16*)(smem + 53248);   // 49152 B (end 102400)
  float* const ly = (float*)smem;                    // 94208 B
  float* const dd = (float*)(smem + 94208);          // 7296 B

  const int tid = threadIdx.x;
  const int lane = tid & 63;
  const int wave = tid >> 6;
  const int j0 = blockIdx.x * BM;
  const int row16 = lane & 15;
  const int quad = lane >> 4;

  floatx4 acc[2][12] = {};

  // A staging coords: thread -> (row 0..31, 4 consecutive k)
  const int arow = tid >> 3;
  const int acol = (tid & 7) * 4;
  const float* const Wrow = W + (size_t)(j0 + arow) * HB + acol;

  // B staging: 48 chunks x (16 rows x 32 k); wave handles 12 chunks.
  // lane l of chunk c: row = c*16 + l/4, k-half offset (l&3)*8.
  const int brow = lane >> 2;
  const int bkoff = (lane & 3) * 8;

  auto stage = [&](int k0, _Float16* Asb, _Float16* Bsb) {
#pragma unroll
    for (int cc = 0; cc < 12; ++cc) {
      const int c = wave * 12 + cc;
      const int row = c * 16 + brow;
      __builtin_amdgcn_global_load_lds(
          (const __attribute__((address_space(1))) void*)(Xh + (size_t)row * HB + k0 + bkoff),
          (__attribute__((address_space(3))) void*)(Bsb + c * 512), 16, 0, 0);
    }
    const float4 w4 = *(const float4*)(Wrow + k0);
    half4v h4;
    h4.x = (_Float16)w4.x;
    h4.y = (_Float16)w4.y;
    h4.z = (_Float16)w4.z;
    h4.w = (_Float16)w4.w;
    *(half4v*)(Asb + arow * 32 + acol) = h4;
  };

  stage(0, As0, Bs0);
  for (int k = 0; k < HB / 32; ++k) {
    const int cur = k & 1;
    _Float16* const Asc = cur ? As1 : As0;
    _Float16* const Bsc = cur ? Bs1 : Bs0;
    if (k + 1 < HB / 32) stage((k + 1) * 32, cur ? As0 : As1, cur ? Bs0 : Bs1);
    __syncthreads();  // buf[cur] staged & visible

    half8 af[2], bf[12];
#pragma unroll
    for (int i = 0; i < 2; ++i)
      af[i] = *(const half8*)(Asc + (i * 16 + row16) * 32 + quad * 8);
#pragma unroll
    for (int jt = 0; jt < 12; ++jt)
      bf[jt] = *(const half8*)(Bsc + (wave * 192 + jt * 16 + row16) * 32 + quad * 8);
#pragma unroll
    for (int i = 0; i < 2; ++i)
#pragma unroll
      for (int jt = 0; jt < 12; ++jt)
        acc[i][jt] = __builtin_amdgcn_mfma_f32_16x16x32_f16(af[i], bf[jt], acc[i][jt], 0, 0, 0);
    __syncthreads();  // reads done before buf[cur] restaged in step k+2
  }

  // ---- epilogue: y = relu(acc + bias) -> LDS ----
  float bv[2][4];
#pragma unroll
  for (int i = 0; i < 2; ++i)
#pragma unroll
    for (int reg = 0; reg < 4; ++reg)
      bv[i][reg] = bias[j0 + i * 16 + quad * 4 + reg];

  // (last loop iteration's trailing barrier: staging LDS is dead; reuse as ly)
#pragma unroll
  for (int i = 0; i < 2; ++i) {
#pragma unroll
    for (int jt = 0; jt < 12; ++jt) {
      const int col = wave * 192 + jt * 16 + row16;
      if (col < YS) {
#pragma unroll
        for (int reg = 0; reg < 4; ++reg) {
          const int row = i * 16 + quad * 4 + reg;
          float v = acc[i][jt][reg] + bv[i][reg];
          ly[row * YS + col] = v > 0.f ? v : 0.f;
        }
      }
    }
  }
  __syncthreads();

  // ---- rowsums -> dd. mixed[r][q] (57x57), r-1 = c*7+n:
  //   rowsum(0)=9; rowsum(r)= (n==6) + sum_p ly[(7*(7-c)+p)*7+n], p=0..55
  for (int idx = tid; idx < BM * NOUT; idx += 256) {
    const int jj = idx / NOUT;
    const int r = idx % NOUT;
    const float* lyj = ly + jj * YS;
    float s;
    if (r == 0) {
      s = 9.f;
    } else {
      const int c = (r - 1) / 7;
      const int n = (r - 1) % 7;
      const int base = 7 * (7 - c);
      s = (n == 6) ? 1.f : 0.f;
#pragma unroll
      for (int p = 0; p < 56; ++p) s += lyj[(base + p) * 7 + n];
    }
    s = s < 1.f ? 1.f : s;
    dd[idx] = rsqrtf(s);
  }
  __syncthreads();

  // ---- output: out[j0+jj][r][q] = dd_r * mixed * dd_q, float4 stores ----
  float4* const o4 = (float4*)(out + (size_t)j0 * (NOUT * NOUT));
  const int total4 = BM * NOUT * NOUT / 4;  // 25992
  for (int idx = tid; idx < total4; idx += 256) {
    float4 v4;
#pragma unroll
    for (int e = 0; e < 4; ++e) {
      const int g = idx * 4 + e;
      const int jj = g / (NOUT * NOUT);
      const int i = g % (NOUT * NOUT);
      const int r = i / NOUT;
      const int q = i % NOUT;
      const float* lyj = ly + jj * YS;
      const float* ddj = dd + jj * NOUT;
      float v;
      if (r == 0) {
        v = (q % 7 == 0) ? ddj[0] * ddj[q] : 0.f;
      } else {
        const int c = (r - 1) / 7;
        const int n = (r - 1) % 7;
        if (q == 0)
          v = (n == 6) ? ddj[r] * ddj[0] : 0.f;
        else
          v = ddj[r] * lyj[(7 * (7 - c) + q - 1) * 7 + n] * ddj[q];
      }
      ((float*)&v4)[e] = v;
    }
    o4[idx] = v4;
  }
}

// ---------------------------------------------------------------------------
extern "C" void kernel_launch(void* const* d_in, const int* in_sizes, int n_in,
                              void* d_out, int out_size, void* d_ws, size_t ws_size,
                              hipStream_t stream) {
  const float* mat = (const float*)d_in[0];  // (1024,7,7)
  const float* tex = (const float*)d_in[1];  // (1024,15)
  const float* W = (const float*)d_in[2];    // (8192,1024)
  const float* b = (const float*)d_in[3];    // (8192,)
  float* out = (float*)d_out;                // (8192,57,57)

  _Float16* Xh = (_Float16*)d_ws;  // 1.5 MB

  prep_x2_kernel<<<NPAD, 256, 0, stream>>>(mat, tex, Xh);
  fused_kernel<<<HM / BM, 256, 102400, stream>>>(W, Xh, b, out);
}

// Round 4
// 193.997 us; speedup vs baseline: 1.3775x; 1.3775x over previous
//
#include <hip/hip_runtime.h>
#include <hip/hip_bf16.h>

// Problem constants
#define HB 1024   // NUM_BASIC (GEMM K)
#define HM 8192   // NUM_MIXED (GEMM M)
#define NR 735    // 105*7 actual GEMM N
#define NPAD 768  // padded N (6 tiles of 128)
#define NOUT 57   // output is (HM, 57, 57)
#define KSPLIT 2  // 768 blocks = 3/CU resident
#define JB 4      // j-rows per epilogue block
#define YS 737    // ly LDS row stride (737%32==1: bank skew)

typedef __attribute__((ext_vector_type(8))) _Float16 half8;
typedef __attribute__((ext_vector_type(4))) _Float16 half4v;
typedef __attribute__((ext_vector_type(4))) float floatx4;

// ---------------------------------------------------------------------------
// Kernel 1: x2[r][h] = relu(te[h,t]*mat[h,n,m]) fp16, padded to 768 rows
// (zeros), K(h)-contiguous. r = (t*7+m)*7 + n
// ---------------------------------------------------------------------------
__global__ __launch_bounds__(256) void prep_x2_kernel(
    const float* __restrict__ mat, const float* __restrict__ tex,
    _Float16* __restrict__ Xh) {
  const int r = blockIdx.x;
  const int n = r % 7;
  const int tm = r / 7;
  const int m = tm % 7;
  const int t = tm / 7;
#pragma unroll
  for (int i = 0; i < 4; ++i) {
    const int h = i * 256 + threadIdx.x;
    float v = 0.f;
    if (r < NR) {
      const float mv = mat[h * 49 + n * 7 + m];
      const float te = 1.f / (1.f + expf(-tex[h * 15 + t])) + 1.f;
      v = te * mv;
      v = v > 0.f ? v : 0.f;  // relu
    }
    Xh[r * HB + h] = (_Float16)v;
  }
}

// ---------------------------------------------------------------------------
// Kernel 2: GEMM partials Yp[ks][j][r] = sum_{k in half ks} W[j][k]*Xh[r][k]
// 128x128x32 tile, 4 waves x (64x64 via 4x4 16x16x32 f16 MFMAs).
// A staged from fp32 W with inline cvt (W is L3-resident; prep_w eliminated).
// B staged via global_load_lds width=16. Partials stored fp16.
// grid (bn=6, bm=64, ks=2) = 768 blocks = 3/CU.
// ---------------------------------------------------------------------------
__global__ __launch_bounds__(256, 3) void gemm_kernel(
    const float* __restrict__ W,      // [8192][1024] fp32
    const _Float16* __restrict__ Xh,  // [768][1024] fp16
    _Float16* __restrict__ Yp) {      // [KSPLIT][8192][768] fp16 partials
  __shared__ __align__(16) _Float16 As[128 * 32];
  __shared__ __align__(16) _Float16 Bs[128 * 32];

  const int tid = threadIdx.x;
  const int lane = tid & 63;
  const int wave = tid >> 6;
  const int bn = blockIdx.x;
  const int bm = blockIdx.y;
  const int ks = blockIdx.z;
  const int wm = (wave >> 1) * 64;
  const int wn = (wave & 1) * 64;

  floatx4 acc[4][4] = {};

  // B staging: 8 chunks of 16 rows x 32 k; wave w covers chunks {2w, 2w+1}.
  const int brow = lane >> 2;
  const int bkh = (lane & 3) * 8;
  const size_t bbase = (size_t)(bn * 128) * HB;

  // A staging: 4 iters; thread covers (row = it*32 + tid/8, k = (tid&7)*4).
  // float4 load (8 threads = 128B coalesced) + cvt + ds_write_b64
  // (2-way bank aliasing only = free per m136).
  const int arow = tid >> 3;
  const int acol = (tid & 7) * 4;
  const float* const Wbase = W + (size_t)(bm * 128) * HB;

  const int mrow = lane & 15;
  const int quad = lane >> 4;

  const int kbeg = ks * (HB / KSPLIT);
  for (int kk = 0; kk < HB / KSPLIT; kk += 32) {
    const int k0 = kbeg + kk;
#pragma unroll
    for (int it = 0; it < 2; ++it) {
      const int chunk = wave * 2 + it;
      __builtin_amdgcn_global_load_lds(
          (const __attribute__((address_space(1))) void*)(
              Xh + bbase + (size_t)(chunk * 16 + brow) * HB + k0 + bkh),
          (__attribute__((address_space(3))) void*)(Bs + chunk * 512), 16, 0, 0);
    }
#pragma unroll
    for (int it = 0; it < 4; ++it) {
      const int r = it * 32 + arow;
      const float4 w4 = *(const float4*)(Wbase + (size_t)r * HB + k0 + acol);
      half4v h4;
      h4.x = (_Float16)w4.x;
      h4.y = (_Float16)w4.y;
      h4.z = (_Float16)w4.z;
      h4.w = (_Float16)w4.w;
      *(half4v*)(As + r * 32 + acol) = h4;
    }
    __syncthreads();  // staged data visible (vmcnt+lgkm drained by barrier)

    half8 af[4], bf[4];
#pragma unroll
    for (int i = 0; i < 4; ++i) {
      af[i] = *(const half8*)(As + (wm + i * 16 + mrow) * 32 + quad * 8);
      bf[i] = *(const half8*)(Bs + (wn + i * 16 + mrow) * 32 + quad * 8);
    }
#pragma unroll
    for (int i = 0; i < 4; ++i)
#pragma unroll
      for (int j = 0; j < 4; ++j)
        acc[i][j] = __builtin_amdgcn_mfma_f32_16x16x32_f16(af[i], bf[j], acc[i][j], 0, 0, 0);
    __syncthreads();  // all reads done before next-step restage
  }

  // raw fp16 partials; bias+relu deferred (needs full-K sum)
  _Float16* const Yk = Yp + (size_t)ks * HM * NPAD;
#pragma unroll
  for (int i = 0; i < 4; ++i) {
#pragma unroll
    for (int j = 0; j < 4; ++j) {
#pragma unroll
      for (int reg = 0; reg < 4; ++reg) {
        const int grow = bm * 128 + wm + i * 16 + quad * 4 + reg;
        const int gcol = bn * 128 + wn + j * 16 + mrow;
        Yk[(size_t)grow * NPAD + gcol] = (_Float16)acc[i][j][reg];
      }
    }
  }
}

// ---------------------------------------------------------------------------
// Kernel 3: epilogue, 4 j per block (2048 blocks = 8/CU).
// y[j, p*7+n] = relu(p0+p1+b[j]); mixed[r][q] (57x57), r-1 = c*7+n:
//   r=0: ones at q%7==0; r>=1: q=0 -> (n==6); q>=1 -> y[j, n, 7*(7-c)+q-1]
// d = rsqrt(max(1,rowsum)); out = d_r*mixed*d_q, written as float4.
// ---------------------------------------------------------------------------
__global__ __launch_bounds__(256) void epilogue_kernel(
    const _Float16* __restrict__ Yp, const float* __restrict__ bias,
    float* __restrict__ out) {
  const int tid = threadIdx.x;
  const int j0 = blockIdx.x * JB;
  __shared__ float ly[JB][YS];
  __shared__ float dd[JB][NOUT];

#pragma unroll
  for (int jj = 0; jj < JB; ++jj) {
    const _Float16* y0 = Yp + (size_t)(j0 + jj) * NPAD;
    const _Float16* y1 = Yp + (size_t)(HM + j0 + jj) * NPAD;
    const float bj = bias[j0 + jj];
    for (int i = tid; i < NR; i += 256) {
      float v = (float)y0[i] + (float)y1[i] + bj;
      ly[jj][i] = v > 0.f ? v : 0.f;
    }
  }
  __syncthreads();

  if (tid < JB * NOUT) {
    const int jj = tid / NOUT;
    const int r = tid % NOUT;
    float s;
    if (r == 0) {
      s = 9.f;
    } else {
      const int c = (r - 1) / 7;
      const int n = (r - 1) % 7;
      const int base = 7 * (7 - c);
      s = (n == 6) ? 1.f : 0.f;
#pragma unroll
      for (int p = 0; p < 56; ++p) s += ly[jj][(base + p) * 7 + n];
    }
    s = s < 1.f ? 1.f : s;
    dd[jj][r] = rsqrtf(s);
  }
  __syncthreads();

  // JB*3249 = 12996 floats = exactly 3249 float4 per block
  float4* const o4 = (float4*)(out + (size_t)j0 * (NOUT * NOUT));
  for (int idx = tid; idx < NOUT * NOUT; idx += 256) {
    float4 v4;
#pragma unroll
    for (int e = 0; e < 4; ++e) {
      const int g = idx * 4 + e;
      const int jj = g / (NOUT * NOUT);
      const int i = g % (NOUT * NOUT);
      const int r = i / NOUT;
      const int q = i % NOUT;
      float v;
      if (r == 0) {
        v = (q % 7 == 0) ? dd[jj][0] * dd[jj][q] : 0.f;
      } else {
        const int c = (r - 1) / 7;
        const int n = (r - 1) % 7;
        if (q == 0)
          v = (n == 6) ? dd[jj][r] * dd[jj][0] : 0.f;
        else
          v = dd[jj][r] * ly[jj][(7 * (7 - c) + q - 1) * 7 + n] * dd[jj][q];
      }
      ((float*)&v4)[e] = v;
    }
    o4[idx] = v4;
  }
}

// ---------------------------------------------------------------------------
extern "C" void kernel_launch(void* const* d_in, const int* in_sizes, int n_in,
                              void* d_out, int out_size, void* d_ws, size_t ws_size,
                              hipStream_t stream) {
  const float* mat = (const float*)d_in[0];  // (1024,7,7)
  const float* tex = (const float*)d_in[1];  // (1024,15)
  const float* W = (const float*)d_in[2];    // (8192,1024)
  const float* b = (const float*)d_in[3];    // (8192,)
  float* out = (float*)d_out;                // (8192,57,57)

  char* ws = (char*)d_ws;
  _Float16* Xh = (_Float16*)ws;                              // 1.5 MB
  _Float16* Yp = (_Float16*)(ws + (size_t)NPAD * HB * 2);    // 2 x 12.6 MB fp16

  prep_x2_kernel<<<NPAD, 256, 0, stream>>>(mat, tex, Xh);
  gemm_kernel<<<dim3(NPAD / 128, HM / 128, KSPLIT), 256, 0, stream>>>(W, Xh, Yp);
  epilogue_kernel<<<HM / JB, 256, 0, stream>>>(Yp, b, out);
}

// Round 5
// 189.756 us; speedup vs baseline: 1.4083x; 1.0223x over previous
//
#include <hip/hip_runtime.h>
#include <hip/hip_bf16.h>

// Problem constants
#define HB 1024   // NUM_BASIC (GEMM K)
#define HM 8192   // NUM_MIXED (GEMM M)
#define NR 735    // 105*7 actual GEMM N
#define NPAD 768  // padded N (6 tiles of 128)
#define NOUT 57   // output is (HM, 57, 57)
#define KSPLIT 2  // 768 blocks = 3/CU resident
#define JB 4      // j-rows per epilogue block
#define YS 740    // ly LDS row stride (740%4==0: float4-aligned rows)
#define CTS 132   // C-transpose LDS stride in halfs (conflict-free)

typedef __attribute__((ext_vector_type(8))) _Float16 half8;
typedef __attribute__((ext_vector_type(4))) _Float16 half4v;
typedef __attribute__((ext_vector_type(4))) float floatx4;

// ---------------------------------------------------------------------------
// Kernel 1 (combined prep):
//  blocks [0, NPAD): x2[r][h] = relu(te[h,t]*mat[h,n,m]) fp16, K-contiguous,
//                    rows >= NR zeroed. r = (t*7+m)*7 + n
//  blocks [NPAD, NPAD+8192): W fp32 -> fp16 (float4 -> half4 stream)
// ---------------------------------------------------------------------------
__global__ __launch_bounds__(256) void prep_kernel(
    const float* __restrict__ mat, const float* __restrict__ tex,
    const float4* __restrict__ W4, _Float16* __restrict__ Xh,
    half4v* __restrict__ Wh4) {
  const int bid = blockIdx.x;
  if (bid < NPAD) {
    const int r = bid;
    const int n = r % 7;
    const int tm = r / 7;
    const int m = tm % 7;
    const int t = tm / 7;
#pragma unroll
    for (int i = 0; i < 4; ++i) {
      const int h = i * 256 + threadIdx.x;
      float v = 0.f;
      if (r < NR) {
        const float mv = mat[h * 49 + n * 7 + m];
        const float te = 1.f / (1.f + expf(-tex[h * 15 + t])) + 1.f;
        v = te * mv;
        v = v > 0.f ? v : 0.f;  // relu
      }
      Xh[r * HB + h] = (_Float16)v;
    }
  } else {
    const int idx = (bid - NPAD) * 256 + threadIdx.x;
    const float4 v = W4[idx];
    half4v h;
    h.x = (_Float16)v.x;
    h.y = (_Float16)v.y;
    h.z = (_Float16)v.z;
    h.w = (_Float16)v.w;
    Wh4[idx] = h;
  }
}

// ---------------------------------------------------------------------------
// Kernel 2: GEMM partials Yp[ks][j][r] = sum_{k in half ks} Wh[j][k]*Xh[r][k]
// 128x128x32 tile, 4 waves x (64x64 via 4x4 16x16x32 f16 MFMAs), both
// operands staged via global_load_lds width=16 (m97 recipe).
// grid (6, 64, 2) = 768 blocks = 3/CU. Partials stored fp16 via LDS
// transpose -> half8 stores (16B/lane, 256B segments).
// ---------------------------------------------------------------------------
__global__ __launch_bounds__(256, 3) void gemm_kernel(
    const _Float16* __restrict__ A,   // Wh [8192][1024] fp16
    const _Float16* __restrict__ B,   // Xh [768][1024] fp16
    _Float16* __restrict__ Yp) {      // [KSPLIT][8192][768] fp16 partials
  // union: staging As[4096] + Bs[4096] halfs, or C-transpose Ct[64*132]
  __shared__ __align__(16) _Float16 smem[64 * CTS];  // 16896 B
  _Float16* const As = smem;
  _Float16* const Bs = smem + 4096;
  _Float16* const Ct = smem;

  const int tid = threadIdx.x;
  const int lane = tid & 63;
  const int wave = tid >> 6;
  const int bn = blockIdx.x;
  const int bm = blockIdx.y;
  const int ks = blockIdx.z;
  const int wm = (wave >> 1) * 64;
  const int wn = (wave & 1) * 64;

  floatx4 acc[4][4] = {};

  // staging: 8 chunks of (16 rows x 32 k); wave w covers chunks {2w, 2w+1}.
  // lane l of chunk c: row = c*16 + l/4, k-offset (l&3)*8 halfs.
  const int srow = lane >> 2;
  const int skh = (lane & 3) * 8;
  const size_t abase = (size_t)(bm * 128) * HB;
  const size_t bbase = (size_t)(bn * 128) * HB;

  const int mrow = lane & 15;
  const int quad = lane >> 4;

  const int kbeg = ks * (HB / KSPLIT);
  for (int kk = 0; kk < HB / KSPLIT; kk += 32) {
    const int k0 = kbeg + kk;
#pragma unroll
    for (int it = 0; it < 2; ++it) {
      const int chunk = wave * 2 + it;
      const int row = chunk * 16 + srow;
      __builtin_amdgcn_global_load_lds(
          (const __attribute__((address_space(1))) void*)(A + abase + (size_t)row * HB + k0 + skh),
          (__attribute__((address_space(3))) void*)(As + chunk * 512), 16, 0, 0);
      __builtin_amdgcn_global_load_lds(
          (const __attribute__((address_space(1))) void*)(B + bbase + (size_t)row * HB + k0 + skh),
          (__attribute__((address_space(3))) void*)(Bs + chunk * 512), 16, 0, 0);
    }
    __syncthreads();  // staged data visible

    half8 af[4], bf[4];
#pragma unroll
    for (int i = 0; i < 4; ++i) {
      af[i] = *(const half8*)(As + (wm + i * 16 + mrow) * 32 + quad * 8);
      bf[i] = *(const half8*)(Bs + (wn + i * 16 + mrow) * 32 + quad * 8);
    }
#pragma unroll
    for (int i = 0; i < 4; ++i)
#pragma unroll
      for (int j = 0; j < 4; ++j)
        acc[i][j] = __builtin_amdgcn_mfma_f32_16x16x32_f16(af[i], bf[j], acc[i][j], 0, 0, 0);
    __syncthreads();  // reads done before next restage
  }

  // ---- store fp16 partials via LDS transpose (two 64-row halves) ----
  // C/D layout: col = mrow, row = quad*4 + reg. Waves {0,1} own rows 0-63
  // (cols 0-63 / 64-127), waves {2,3} rows 64-127.
  _Float16* const Yk = Yp + (size_t)ks * HM * NPAD;
#pragma unroll
  for (int half = 0; half < 2; ++half) {
    if ((wave >> 1) == half) {
#pragma unroll
      for (int i = 0; i < 4; ++i)
#pragma unroll
        for (int j = 0; j < 4; ++j)
#pragma unroll
          for (int reg = 0; reg < 4; ++reg)
            Ct[(i * 16 + quad * 4 + reg) * CTS + wn + j * 16 + mrow] =
                (_Float16)acc[i][j][reg];
    }
    __syncthreads();
#pragma unroll
    for (int s = 0; s < 4; ++s) {
      const int cid = s * 256 + tid;
      const int row = cid >> 4;   // 0..63
      const int c8 = cid & 15;    // 16B chunk within 128-col row
      const half8 v = *(const half8*)(Ct + row * CTS + c8 * 8);
      *(half8*)(Yk + (size_t)(bm * 128 + half * 64 + row) * NPAD + bn * 128 + c8 * 8) = v;
    }
    __syncthreads();  // Ct free before next half overwrites
  }
}

// ---------------------------------------------------------------------------
// Kernel 3: epilogue, 4 j per block (2048 blocks = 8/CU).
// y[j, p*7+n] = relu(p0+p1+b[j]); mixed[r][q] (57x57), r-1 = c*7+n:
//   r=0: ones at q%7==0; r>=1: q=0 -> (n==6); q>=1 -> y[j, n, 7*(7-c)+q-1]
// d = rsqrt(max(1,rowsum)); out = d_r*mixed*d_q, float4 stores.
// ---------------------------------------------------------------------------
__global__ __launch_bounds__(256) void epilogue_kernel(
    const _Float16* __restrict__ Yp, const float* __restrict__ bias,
    float* __restrict__ out) {
  const int tid = threadIdx.x;
  const int j0 = blockIdx.x * JB;
  __shared__ float ly[JB][YS];
  __shared__ float dd[JB][NOUT];

  // phase 1: vectorized partial-sum + bias + relu. 92 half8 chunks cover
  // halfs 0..735 (pad cols are zeros from the GEMM's zero B rows).
  for (int idx = tid; idx < JB * 92; idx += 256) {
    const int jj = idx / 92;
    const int c8 = idx % 92;
    const half8 a = *(const half8*)(Yp + (size_t)(j0 + jj) * NPAD + c8 * 8);
    const half8 b2 = *(const half8*)(Yp + (size_t)(HM + j0 + jj) * NPAD + c8 * 8);
    const float bj = bias[j0 + jj];
    float4 lo, hi;
#pragma unroll
    for (int e = 0; e < 4; ++e) {
      float v = (float)a[e] + (float)b2[e] + bj;
      ((float*)&lo)[e] = v > 0.f ? v : 0.f;
    }
#pragma unroll
    for (int e = 0; e < 4; ++e) {
      float v = (float)a[4 + e] + (float)b2[4 + e] + bj;
      ((float*)&hi)[e] = v > 0.f ? v : 0.f;
    }
    *(float4*)(&ly[jj][c8 * 8]) = lo;
    *(float4*)(&ly[jj][c8 * 8 + 4]) = hi;
  }
  __syncthreads();

  if (tid < JB * NOUT) {
    const int jj = tid / NOUT;
    const int r = tid % NOUT;
    float s;
    if (r == 0) {
      s = 9.f;
    } else {
      const int c = (r - 1) / 7;
      const int n = (r - 1) % 7;
      const int base = 7 * (7 - c);
      s = (n == 6) ? 1.f : 0.f;
#pragma unroll
      for (int p = 0; p < 56; ++p) s += ly[jj][(base + p) * 7 + n];
    }
    s = s < 1.f ? 1.f : s;
    dd[jj][r] = rsqrtf(s);
  }
  __syncthreads();

  // JB*3249 floats = exactly 3249 float4 per block
  float4* const o4 = (float4*)(out + (size_t)j0 * (NOUT * NOUT));
  for (int idx = tid; idx < NOUT * NOUT; idx += 256) {
    float4 v4;
#pragma unroll
    for (int e = 0; e < 4; ++e) {
      const int g = idx * 4 + e;
      const int jj = g / (NOUT * NOUT);
      const int i = g % (NOUT * NOUT);
      const int r = i / NOUT;
      const int q = i % NOUT;
      float v;
      if (r == 0) {
        v = (q % 7 == 0) ? dd[jj][0] * dd[jj][q] : 0.f;
      } else {
        const int c = (r - 1) / 7;
        const int n = (r - 1) % 7;
        if (q == 0)
          v = (n == 6) ? dd[jj][r] * dd[jj][0] : 0.f;
        else
          v = dd[jj][r] * ly[jj][(7 * (7 - c) + q - 1) * 7 + n] * dd[jj][q];
      }
      ((float*)&v4)[e] = v;
    }
    o4[idx] = v4;
  }
}

// ---------------------------------------------------------------------------
extern "C" void kernel_launch(void* const* d_in, const int* in_sizes, int n_in,
                              void* d_out, int out_size, void* d_ws, size_t ws_size,
                              hipStream_t stream) {
  const float* mat = (const float*)d_in[0];  // (1024,7,7)
  const float* tex = (const float*)d_in[1];  // (1024,15)
  const float* W = (const float*)d_in[2];    // (8192,1024)
  const float* b = (const float*)d_in[3];    // (8192,)
  float* out = (float*)d_out;                // (8192,57,57)

  char* ws = (char*)d_ws;
  _Float16* Xh = (_Float16*)ws;                                   // 1.5 MB
  _Float16* Wh = (_Float16*)(ws + (size_t)NPAD * HB * 2);         // 16.8 MB
  _Float16* Yp = (_Float16*)(ws + (size_t)(NPAD + HM) * HB * 2);  // 2 x 12.6 MB

  prep_kernel<<<NPAD + HM * HB / 4 / 256, 256, 0, stream>>>(
      mat, tex, (const float4*)W, Xh, (half4v*)Wh);
  gemm_kernel<<<dim3(NPAD / 128, HM / 128, KSPLIT), 256, 0, stream>>>(Wh, Xh, Yp);
  epilogue_kernel<<<HM / JB, 256, 0, stream>>>(Yp, b, out);
}